// Round 1
// baseline (363.978 us; speedup 1.0000x reference)
//
#include <hip/hip_runtime.h>

// PrecRec: confusion-matrix counts over 10 sigmoid thresholds.
// sigmoid(x) > t  <=>  x > logit(t); logits hardcoded for t = j/11, j=1..10.
// One streaming pass (memory-bound, ~402 MB), register accumulators,
// wave64 shuffle reduce -> LDS block reduce -> strided global atomics.

#define NTHR 10
#define NCNT 22            // [0..9]=tp, [10..19]=p, [20]=sum(m), [21]=sum(m&t)
#define WS_STRIDE 16       // uints => 64 B between counters (spread atomics across lines)

__device__ __forceinline__ unsigned wave_reduce_add(unsigned v) {
#pragma unroll
    for (int off = 32; off > 0; off >>= 1)
        v += __shfl_down(v, off, 64);
    return v;
}

__global__ __launch_bounds__(64) void zero_ws_kernel(unsigned* __restrict__ ws) {
    int i = threadIdx.x;
    if (i < NCNT) ws[i * WS_STRIDE] = 0u;
}

__global__ __launch_bounds__(256) void count_kernel(
        const float4* __restrict__ pred4,
        const int4*  __restrict__ mask4,
        const int4*  __restrict__ targ4,
        const float* __restrict__ pred,
        const int*   __restrict__ mask,
        const int*   __restrict__ targ,
        unsigned* __restrict__ ws, int nvec, int n) {
    // logit(j/11) = ln(j/(11-j))
    const float L[NTHR] = {-2.3025851f, -1.5040774f, -0.98082925f, -0.55961579f,
                           -0.18232156f, 0.18232156f,  0.55961579f,  0.98082925f,
                            1.5040774f,  2.3025851f};
    unsigned accTP[NTHR] = {}, accP[NTHR] = {};
    unsigned accM = 0u, accMT = 0u;

    const int idx    = blockIdx.x * blockDim.x + threadIdx.x;
    const int stride = gridDim.x * blockDim.x;

    for (int i = idx; i < nvec; i += stride) {
        float4 p = pred4[i];
        int4   m = mask4[i];
        int4   t = targ4[i];
        float    pv[4] = {p.x, p.y, p.z, p.w};
        unsigned mv[4] = {(unsigned)m.x, (unsigned)m.y, (unsigned)m.z, (unsigned)m.w};
        unsigned tv[4] = {(unsigned)t.x, (unsigned)t.y, (unsigned)t.z, (unsigned)t.w};
#pragma unroll
        for (int c = 0; c < 4; ++c) {
            unsigned mm = mv[c];
            unsigned mt = mm & tv[c];
            accM  += mm;
            accMT += mt;
#pragma unroll
            for (int j = 0; j < NTHR; ++j) {
                bool pos = pv[c] > L[j];
                accP[j]  += pos ? mm : 0u;
                accTP[j] += pos ? mt : 0u;
            }
        }
    }
    // scalar tail (n % 4), handled by first few global threads
    int rem = n & 3;
    if (idx < rem) {
        int i = nvec * 4 + idx;
        float    pv = pred[i];
        unsigned mm = (unsigned)mask[i];
        unsigned mt = mm & (unsigned)targ[i];
        accM += mm; accMT += mt;
#pragma unroll
        for (int j = 0; j < NTHR; ++j) {
            bool pos = pv > L[j];
            accP[j]  += pos ? mm : 0u;
            accTP[j] += pos ? mt : 0u;
        }
    }

    unsigned vals[NCNT];
#pragma unroll
    for (int j = 0; j < NTHR; ++j) { vals[j] = accTP[j]; vals[NTHR + j] = accP[j]; }
    vals[20] = accM;
    vals[21] = accMT;
#pragma unroll
    for (int c = 0; c < NCNT; ++c) vals[c] = wave_reduce_add(vals[c]);

    __shared__ unsigned partial[4][NCNT];
    const int wave = threadIdx.x >> 6;
    const int lane = threadIdx.x & 63;
    if (lane == 0) {
#pragma unroll
        for (int c = 0; c < NCNT; ++c) partial[wave][c] = vals[c];
    }
    __syncthreads();
    if (threadIdx.x < NCNT) {
        unsigned s = partial[0][threadIdx.x] + partial[1][threadIdx.x] +
                     partial[2][threadIdx.x] + partial[3][threadIdx.x];
        atomicAdd(&ws[threadIdx.x * WS_STRIDE], s);
    }
}

__global__ __launch_bounds__(64) void finalize_kernel(const unsigned* __restrict__ ws,
                                                      float* __restrict__ out) {
    int j = threadIdx.x;
    if (j < NTHR) {
        unsigned tp = ws[j * WS_STRIDE];
        unsigned p  = ws[(NTHR + j) * WS_STRIDE];
        unsigned tm = ws[20 * WS_STRIDE];
        unsigned tt = ws[21 * WS_STRIDE];
        unsigned fp = p - tp;
        unsigned fn = tt - tp;
        unsigned tn = tm - p - fn;
        out[j]            = (float)tp;
        out[NTHR + j]     = (float)fp;
        out[2 * NTHR + j] = (float)tn;
        out[3 * NTHR + j] = (float)fn;
    }
}

extern "C" void kernel_launch(void* const* d_in, const int* in_sizes, int n_in,
                              void* d_out, int out_size, void* d_ws, size_t ws_size,
                              hipStream_t stream) {
    const float* pred = (const float*)d_in[0];
    const int*   mask = (const int*)d_in[1];
    const int*   targ = (const int*)d_in[2];
    unsigned*    ws   = (unsigned*)d_ws;
    float*       out  = (float*)d_out;

    const int n    = in_sizes[0];
    const int nvec = n / 4;

    zero_ws_kernel<<<1, 64, 0, stream>>>(ws);

    // 2048 blocks x 256 threads = 8192 waves: fills 256 CUs at 32 waves/CU.
    const int blocks = 2048;
    count_kernel<<<blocks, 256, 0, stream>>>(
        (const float4*)pred, (const int4*)mask, (const int4*)targ,
        pred, mask, targ, ws, nvec, n);

    finalize_kernel<<<1, 64, 0, stream>>>(ws, out);
}

// Round 2
// 362.852 us; speedup vs baseline: 1.0031x; 1.0031x over previous
//
#include <hip/hip_runtime.h>

// PrecRec: confusion-matrix counts over 10 sigmoid thresholds.
// sigmoid(x) > t  <=>  x > logit(t); logits hardcoded for t = j/11, j=1..10.
//
// R2: bucket-histogram scheme. Per element compute bucket b = #(x > L[j])
// (exact same compares as R1, absmax was 0.0), then single shifted-add into
// two packed 64-bit histograms (5-bit fields x 11 buckets). Flush to 32-bit
// per-bucket regs every 24 elements. p[j]/tp[j] = suffix sums (finalize).
// 2-way ILP: two coalesced half-array streams per iteration.

#define NTHR 10
#define NBKT 11            // bucket = 0..10 thresholds passed
#define NCNT 22            // [0..10]=P-bucket counts, [11..21]=TP-bucket counts
#define WS_STRIDE 16       // 64 B between counters

__device__ __forceinline__ unsigned wave_reduce_add(unsigned v) {
#pragma unroll
    for (int off = 32; off > 0; off >>= 1)
        v += __shfl_down(v, off, 64);
    return v;
}

__global__ __launch_bounds__(64) void zero_ws_kernel(unsigned* __restrict__ ws) {
    int i = threadIdx.x;
    if (i < NCNT) ws[i * WS_STRIDE] = 0u;
}

__device__ __forceinline__ void proc_elem(float pv, unsigned mm, unsigned tt,
                                          const float* L,
                                          unsigned long long& hP,
                                          unsigned long long& hT) {
    unsigned mt = mm & tt;
    unsigned b = 0u;
#pragma unroll
    for (int j = 0; j < NTHR; ++j) b += (pv > L[j]) ? 1u : 0u;   // cmp + addc
    unsigned sh = (b << 2) + b;                                   // b*5
    hP += (unsigned long long)mm << sh;
    hT += (unsigned long long)mt << sh;
}

__device__ __forceinline__ void flush_hist(unsigned long long& hP,
                                           unsigned long long& hT,
                                           unsigned* cP, unsigned* cT) {
#pragma unroll
    for (int b = 0; b < NBKT; ++b) {
        cP[b] += (unsigned)(hP >> (5 * b)) & 31u;
        cT[b] += (unsigned)(hT >> (5 * b)) & 31u;
    }
    hP = 0ull; hT = 0ull;
}

__global__ __launch_bounds__(256) void count_kernel(
        const float4* __restrict__ pred4,
        const int4*  __restrict__ mask4,
        const int4*  __restrict__ targ4,
        const float* __restrict__ pred,
        const int*   __restrict__ mask,
        const int*   __restrict__ targ,
        unsigned* __restrict__ ws, int half, int n) {
    // logit(j/11) = ln(j/(11-j))
    const float L[NTHR] = {-2.3025851f, -1.5040774f, -0.98082925f, -0.55961579f,
                           -0.18232156f, 0.18232156f,  0.55961579f,  0.98082925f,
                            1.5040774f,  2.3025851f};
    unsigned cP[NBKT] = {}, cT[NBKT] = {};
    unsigned long long hP = 0ull, hT = 0ull;

    const int idx    = blockIdx.x * blockDim.x + threadIdx.x;
    const int stride = gridDim.x * blockDim.x;

    int fcnt = 0;
    for (int i = idx; i < half; i += stride) {
        // two coalesced streams, 6 x 16B loads issued before any use
        float4 p0 = pred4[i];
        float4 p1 = pred4[i + half];
        int4   m0 = mask4[i];
        int4   m1 = mask4[i + half];
        int4   t0 = targ4[i];
        int4   t1 = targ4[i + half];

        proc_elem(p0.x, (unsigned)m0.x, (unsigned)t0.x, L, hP, hT);
        proc_elem(p0.y, (unsigned)m0.y, (unsigned)t0.y, L, hP, hT);
        proc_elem(p0.z, (unsigned)m0.z, (unsigned)t0.z, L, hP, hT);
        proc_elem(p0.w, (unsigned)m0.w, (unsigned)t0.w, L, hP, hT);
        proc_elem(p1.x, (unsigned)m1.x, (unsigned)t1.x, L, hP, hT);
        proc_elem(p1.y, (unsigned)m1.y, (unsigned)t1.y, L, hP, hT);
        proc_elem(p1.z, (unsigned)m1.z, (unsigned)t1.z, L, hP, hT);
        proc_elem(p1.w, (unsigned)m1.w, (unsigned)t1.w, L, hP, hT);

        // 8 elems/iter: flush every 3 iters -> max 24 < 31 per 5-bit field
        if (++fcnt == 3) { flush_hist(hP, hT, cP, cT); fcnt = 0; }
    }
    flush_hist(hP, hT, cP, cT);

    // scalar tail: elements [half*8, n), at most 11 of them
    {
        int tail_base = half * 8;
        int i = tail_base + idx;
        if (i < n) {
            proc_elem(pred[i], (unsigned)mask[i], (unsigned)targ[i], L, hP, hT);
            flush_hist(hP, hT, cP, cT);
        }
    }

    unsigned vals[NCNT];
#pragma unroll
    for (int b = 0; b < NBKT; ++b) { vals[b] = cP[b]; vals[NBKT + b] = cT[b]; }
#pragma unroll
    for (int c = 0; c < NCNT; ++c) vals[c] = wave_reduce_add(vals[c]);

    __shared__ unsigned partial[4][NCNT];
    const int wave = threadIdx.x >> 6;
    const int lane = threadIdx.x & 63;
    if (lane == 0) {
#pragma unroll
        for (int c = 0; c < NCNT; ++c) partial[wave][c] = vals[c];
    }
    __syncthreads();
    if (threadIdx.x < NCNT) {
        unsigned s = partial[0][threadIdx.x] + partial[1][threadIdx.x] +
                     partial[2][threadIdx.x] + partial[3][threadIdx.x];
        atomicAdd(&ws[threadIdx.x * WS_STRIDE], s);
    }
}

__global__ __launch_bounds__(64) void finalize_kernel(const unsigned* __restrict__ ws,
                                                      float* __restrict__ out) {
    int j = threadIdx.x;
    if (j < NTHR) {
        unsigned totM = 0u, totT = 0u, p = 0u, tp = 0u;
#pragma unroll
        for (int b = 0; b < NBKT; ++b) {
            unsigned vP = ws[b * WS_STRIDE];
            unsigned vT = ws[(NBKT + b) * WS_STRIDE];
            totM += vP; totT += vT;
            if (b > j) { p += vP; tp += vT; }
        }
        unsigned fp = p - tp;
        unsigned fn = totT - tp;
        unsigned tn = totM - p - fn;
        out[j]            = (float)tp;
        out[NTHR + j]     = (float)fp;
        out[2 * NTHR + j] = (float)tn;
        out[3 * NTHR + j] = (float)fn;
    }
}

extern "C" void kernel_launch(void* const* d_in, const int* in_sizes, int n_in,
                              void* d_out, int out_size, void* d_ws, size_t ws_size,
                              hipStream_t stream) {
    const float* pred = (const float*)d_in[0];
    const int*   mask = (const int*)d_in[1];
    const int*   targ = (const int*)d_in[2];
    unsigned*    ws   = (unsigned*)d_ws;
    float*       out  = (float*)d_out;

    const int n    = in_sizes[0];
    const int nvec = n / 4;
    const int half = nvec / 2;

    zero_ws_kernel<<<1, 64, 0, stream>>>(ws);

    const int blocks = 2048;   // 8192 waves across 256 CUs
    count_kernel<<<blocks, 256, 0, stream>>>(
        (const float4*)pred, (const int4*)mask, (const int4*)targ,
        pred, mask, targ, ws, half, n);

    finalize_kernel<<<1, 64, 0, stream>>>(ws, out);
}

// Round 3
// 356.885 us; speedup vs baseline: 1.0199x; 1.0167x over previous
//
#include <hip/hip_runtime.h>

// PrecRec: confusion-matrix counts over 10 sigmoid thresholds.
// sigmoid(x) > t  <=>  x > logit(t); logits hardcoded for t = j/11, j=1..10.
//
// R3: attack memory-level parallelism. R1/R2 both pinned at ~2.8 TB/s with
// VALU <27% and VGPR_Count=32 (compiler serialized loads to stay lean).
// - Wave-contiguous batch-4: 12 x 16B loads issued per iteration per wave
//   (4 KB contiguous per array), one addr reg + immediate offsets.
// - Two-level packed histograms replace the 22-reg accumulator array:
//   level-1: 11 x 5-bit fields in one u64 (<=16 elems/iter, cap 31)
//   level-2: 11 x 10-bit fields across two u64 (<=65 elems/thread, cap 1023)
//   => accumulator state is 12 VGPRs, freeing headroom for load results.

#define NTHR 10
#define NBKT 11            // bucket = #thresholds passed, 0..10
#define NCNT 22            // ws: [0..10]=P-bucket counts, [11..21]=TP-bucket
#define WS_STRIDE 16       // 64 B between counters

__device__ __forceinline__ unsigned wave_reduce_add(unsigned v) {
#pragma unroll
    for (int off = 32; off > 0; off >>= 1)
        v += __shfl_down(v, off, 64);
    return v;
}

__global__ __launch_bounds__(64) void zero_ws_kernel(unsigned* __restrict__ ws) {
    int i = threadIdx.x;
    if (i < NCNT) ws[i * WS_STRIDE] = 0u;
}

__device__ __forceinline__ void acc_elem(float pv, unsigned mm, unsigned tt,
                                         unsigned long long& hP,
                                         unsigned long long& hT) {
    // logit(j/11) = ln(j/(11-j))
    const float L[NTHR] = {-2.3025851f, -1.5040774f, -0.98082925f, -0.55961579f,
                           -0.18232156f, 0.18232156f,  0.55961579f,  0.98082925f,
                            1.5040774f,  2.3025851f};
    unsigned mt = mm & tt;
    unsigned b = 0u;
#pragma unroll
    for (int j = 0; j < NTHR; ++j) b += (pv > L[j]) ? 1u : 0u;
    unsigned sh = (b << 2) + b;                       // b*5
    hP += (unsigned long long)mm << sh;
    hT += (unsigned long long)mt << sh;
}

__device__ __forceinline__ void acc_vec(const float4& p, const int4& m, const int4& t,
                                        unsigned long long& hP,
                                        unsigned long long& hT) {
    acc_elem(p.x, (unsigned)m.x, (unsigned)t.x, hP, hT);
    acc_elem(p.y, (unsigned)m.y, (unsigned)t.y, hP, hT);
    acc_elem(p.z, (unsigned)m.z, (unsigned)t.z, hP, hT);
    acc_elem(p.w, (unsigned)m.w, (unsigned)t.w, hP, hT);
}

__device__ __forceinline__ void flush_hist(unsigned long long& hP, unsigned long long& hT,
                                           unsigned long long& Plo, unsigned long long& Phi,
                                           unsigned long long& Tlo, unsigned long long& Thi) {
#pragma unroll
    for (int b = 0; b < 6; ++b) {
        Plo += (unsigned long long)((unsigned)(hP >> (5 * b)) & 31u) << (10 * b);
        Tlo += (unsigned long long)((unsigned)(hT >> (5 * b)) & 31u) << (10 * b);
    }
#pragma unroll
    for (int b = 6; b < NBKT; ++b) {
        Phi += (unsigned long long)((unsigned)(hP >> (5 * b)) & 31u) << (10 * (b - 6));
        Thi += (unsigned long long)((unsigned)(hT >> (5 * b)) & 31u) << (10 * (b - 6));
    }
    hP = 0ull; hT = 0ull;
}

__global__ __launch_bounds__(256) void count_kernel(
        const float4* __restrict__ pred4,
        const int4*  __restrict__ mask4,
        const int4*  __restrict__ targ4,
        const float* __restrict__ pred,
        const int*   __restrict__ mask,
        const int*   __restrict__ targ,
        unsigned* __restrict__ ws, int nvec, int n) {
    unsigned long long Plo = 0ull, Phi = 0ull, Tlo = 0ull, Thi = 0ull;

    const int tid    = blockIdx.x * blockDim.x + threadIdx.x;
    const int lane   = tid & 63;
    const int waveId = tid >> 6;
    const int totalWaves = (gridDim.x * blockDim.x) >> 6;
    const int strideG    = totalWaves << 8;     // waves * 256 groups

    for (int base = waveId << 8; base < nvec; base += strideG) {
        unsigned long long hP = 0ull, hT = 0ull;
        if (base + 256 <= nvec) {
            // 12 independent 16B loads, issued before any use
            float4 p0 = pred4[base +        lane];
            float4 p1 = pred4[base +  64  + lane];
            float4 p2 = pred4[base + 128  + lane];
            float4 p3 = pred4[base + 192  + lane];
            int4   m0 = mask4[base +        lane];
            int4   m1 = mask4[base +  64  + lane];
            int4   m2 = mask4[base + 128  + lane];
            int4   m3 = mask4[base + 192  + lane];
            int4   t0 = targ4[base +        lane];
            int4   t1 = targ4[base +  64  + lane];
            int4   t2 = targ4[base + 128  + lane];
            int4   t3 = targ4[base + 192  + lane];
            acc_vec(p0, m0, t0, hP, hT);
            acc_vec(p1, m1, t1, hP, hT);
            acc_vec(p2, m2, t2, hP, hT);
            acc_vec(p3, m3, t3, hP, hT);
        } else {
#pragma unroll
            for (int c = 0; c < 4; ++c) {
                int g = base + (c << 6) + lane;
                if (g < nvec)
                    acc_vec(pred4[g], mask4[g], targ4[g], hP, hT);
            }
        }
        flush_hist(hP, hT, Plo, Phi, Tlo, Thi);   // <=16 elems per 5-bit field
    }

    // scalar tail (n % 4)
    {
        int i = nvec * 4 + tid;
        if (i < n) {
            unsigned long long hP = 0ull, hT = 0ull;
            acc_elem(pred[i], (unsigned)mask[i], (unsigned)targ[i], hP, hT);
            flush_hist(hP, hT, Plo, Phi, Tlo, Thi);
        }
    }

    // unpack level-2 (10-bit fields, per-thread max 65 < 1023)
    unsigned vals[NCNT];
#pragma unroll
    for (int b = 0; b < 6; ++b) {
        vals[b]        = (unsigned)(Plo >> (10 * b)) & 1023u;
        vals[NBKT + b] = (unsigned)(Tlo >> (10 * b)) & 1023u;
    }
#pragma unroll
    for (int b = 6; b < NBKT; ++b) {
        vals[b]        = (unsigned)(Phi >> (10 * (b - 6))) & 1023u;
        vals[NBKT + b] = (unsigned)(Thi >> (10 * (b - 6))) & 1023u;
    }
#pragma unroll
    for (int c = 0; c < NCNT; ++c) vals[c] = wave_reduce_add(vals[c]);

    __shared__ unsigned partial[4][NCNT];
    const int wave = threadIdx.x >> 6;
    if ((threadIdx.x & 63) == 0) {
#pragma unroll
        for (int c = 0; c < NCNT; ++c) partial[wave][c] = vals[c];
    }
    __syncthreads();
    if (threadIdx.x < NCNT) {
        unsigned s = partial[0][threadIdx.x] + partial[1][threadIdx.x] +
                     partial[2][threadIdx.x] + partial[3][threadIdx.x];
        atomicAdd(&ws[threadIdx.x * WS_STRIDE], s);
    }
}

__global__ __launch_bounds__(64) void finalize_kernel(const unsigned* __restrict__ ws,
                                                      float* __restrict__ out) {
    int j = threadIdx.x;
    if (j < NTHR) {
        unsigned totM = 0u, totT = 0u, p = 0u, tp = 0u;
#pragma unroll
        for (int b = 0; b < NBKT; ++b) {
            unsigned vP = ws[b * WS_STRIDE];
            unsigned vT = ws[(NBKT + b) * WS_STRIDE];
            totM += vP; totT += vT;
            if (b > j) { p += vP; tp += vT; }
        }
        unsigned fp = p - tp;
        unsigned fn = totT - tp;
        unsigned tn = totM - p - fn;
        out[j]            = (float)tp;
        out[NTHR + j]     = (float)fp;
        out[2 * NTHR + j] = (float)tn;
        out[3 * NTHR + j] = (float)fn;
    }
}

extern "C" void kernel_launch(void* const* d_in, const int* in_sizes, int n_in,
                              void* d_out, int out_size, void* d_ws, size_t ws_size,
                              hipStream_t stream) {
    const float* pred = (const float*)d_in[0];
    const int*   mask = (const int*)d_in[1];
    const int*   targ = (const int*)d_in[2];
    unsigned*    ws   = (unsigned*)d_ws;
    float*       out  = (float*)d_out;

    const int n    = in_sizes[0];
    const int nvec = n / 4;

    zero_ws_kernel<<<1, 64, 0, stream>>>(ws);

    const int blocks = 2048;
    count_kernel<<<blocks, 256, 0, stream>>>(
        (const float4*)pred, (const int4*)mask, (const int4*)targ,
        pred, mask, targ, ws, nvec, n);

    finalize_kernel<<<1, 64, 0, stream>>>(ws, out);
}

// Round 4
// 355.488 us; speedup vs baseline: 1.0239x; 1.0039x over previous
//
#include <hip/hip_runtime.h>

// PrecRec: confusion-matrix counts over 10 sigmoid thresholds.
// sigmoid(x) > t  <=>  x > logit(t); logits hardcoded for t = j/11, j=1..10.
//
// R4: force memory-level parallelism. R3 kept VGPR_Count=32 -> compiler
// serialized the 12-load batch. Evidence says not HBM-bound (L3-served
// replays run at identical dur); it's latency x MLP. So:
//  - explicit software pipeline: iteration i+1's 12x16B loads are issued
//    into 'nxt' registers BEFORE processing iteration i's 'cur' registers
//    (live ranges force the allocator to keep ~96 VGPRs of loads in flight)
//  - __launch_bounds__(256,2): allow low occupancy / high VGPR so the
//    pressure heuristic doesn't re-serialize.
// Math unchanged from R2/R3 (exact compares, packed u64 histograms, absmax 0).

#define NTHR 10
#define NBKT 11            // bucket = #thresholds passed, 0..10
#define NCNT 22            // ws: [0..10]=P-bucket counts, [11..21]=TP-bucket
#define WS_STRIDE 16       // 64 B between counters

typedef unsigned long long u64;

__device__ __forceinline__ unsigned wave_reduce_add(unsigned v) {
#pragma unroll
    for (int off = 32; off > 0; off >>= 1)
        v += __shfl_down(v, off, 64);
    return v;
}

__global__ __launch_bounds__(64) void zero_ws_kernel(unsigned* __restrict__ ws) {
    int i = threadIdx.x;
    if (i < NCNT) ws[i * WS_STRIDE] = 0u;
}

__device__ __forceinline__ void acc_elem(float pv, unsigned mm, unsigned tt,
                                         u64& hP, u64& hT) {
    // logit(j/11) = ln(j/(11-j))
    const float L[NTHR] = {-2.3025851f, -1.5040774f, -0.98082925f, -0.55961579f,
                           -0.18232156f, 0.18232156f,  0.55961579f,  0.98082925f,
                            1.5040774f,  2.3025851f};
    unsigned mt = mm & tt;
    unsigned b = 0u;
#pragma unroll
    for (int j = 0; j < NTHR; ++j) b += (pv > L[j]) ? 1u : 0u;
    unsigned sh = (b << 2) + b;                       // b*5
    hP += (u64)mm << sh;
    hT += (u64)mt << sh;
}

__device__ __forceinline__ void acc_vec(const float4& p, const int4& m, const int4& t,
                                        u64& hP, u64& hT) {
    acc_elem(p.x, (unsigned)m.x, (unsigned)t.x, hP, hT);
    acc_elem(p.y, (unsigned)m.y, (unsigned)t.y, hP, hT);
    acc_elem(p.z, (unsigned)m.z, (unsigned)t.z, hP, hT);
    acc_elem(p.w, (unsigned)m.w, (unsigned)t.w, hP, hT);
}

__device__ __forceinline__ void flush_hist(u64& hP, u64& hT,
                                           u64& Plo, u64& Phi, u64& Tlo, u64& Thi) {
#pragma unroll
    for (int b = 0; b < 6; ++b) {
        Plo += (u64)((unsigned)(hP >> (5 * b)) & 31u) << (10 * b);
        Tlo += (u64)((unsigned)(hT >> (5 * b)) & 31u) << (10 * b);
    }
#pragma unroll
    for (int b = 6; b < NBKT; ++b) {
        Phi += (u64)((unsigned)(hP >> (5 * b)) & 31u) << (10 * (b - 6));
        Thi += (u64)((unsigned)(hT >> (5 * b)) & 31u) << (10 * (b - 6));
    }
    hP = 0ull; hT = 0ull;
}

__global__ __launch_bounds__(256, 2) void count_kernel(
        const float4* __restrict__ pred4,
        const int4*  __restrict__ mask4,
        const int4*  __restrict__ targ4,
        const float* __restrict__ pred,
        const int*   __restrict__ mask,
        const int*   __restrict__ targ,
        unsigned* __restrict__ ws, int nvec, int n) {
    u64 Plo = 0ull, Phi = 0ull, Tlo = 0ull, Thi = 0ull;

    const int tid    = blockIdx.x * blockDim.x + threadIdx.x;
    const int lane   = tid & 63;
    const int waveId = tid >> 6;
    const int totalWaves = (gridDim.x * blockDim.x) >> 6;
    const int strideG    = totalWaves << 8;     // waves * 256 groups/iter

    // ---- software-pipelined main loop: load i+1 before processing i ----
    float4 cp0, cp1, cp2, cp3;
    int4   cm0, cm1, cm2, cm3, ct0, ct1, ct2, ct3;

    int  base = waveId << 8;
    bool full = (base + 256 <= nvec);
    if (full) {
        cp0 = pred4[base +       lane]; cp1 = pred4[base +  64 + lane];
        cp2 = pred4[base + 128 + lane]; cp3 = pred4[base + 192 + lane];
        cm0 = mask4[base +       lane]; cm1 = mask4[base +  64 + lane];
        cm2 = mask4[base + 128 + lane]; cm3 = mask4[base + 192 + lane];
        ct0 = targ4[base +       lane]; ct1 = targ4[base +  64 + lane];
        ct2 = targ4[base + 128 + lane]; ct3 = targ4[base + 192 + lane];
    }

    while (base < nvec) {
        const int nb    = base + strideG;
        const bool nfull = (nb + 256 <= nvec);

        float4 np0, np1, np2, np3;
        int4   nm0, nm1, nm2, nm3, nt0, nt1, nt2, nt3;
        if (nfull) {
            np0 = pred4[nb +       lane]; np1 = pred4[nb +  64 + lane];
            np2 = pred4[nb + 128 + lane]; np3 = pred4[nb + 192 + lane];
            nm0 = mask4[nb +       lane]; nm1 = mask4[nb +  64 + lane];
            nm2 = mask4[nb + 128 + lane]; nm3 = mask4[nb + 192 + lane];
            nt0 = targ4[nb +       lane]; nt1 = targ4[nb +  64 + lane];
            nt2 = targ4[nb + 128 + lane]; nt3 = targ4[nb + 192 + lane];
        }

        u64 hP = 0ull, hT = 0ull;
        if (full) {
            acc_vec(cp0, cm0, ct0, hP, hT);
            acc_vec(cp1, cm1, ct1, hP, hT);
            acc_vec(cp2, cm2, ct2, hP, hT);
            acc_vec(cp3, cm3, ct3, hP, hT);
        } else {
            // ragged last chunk: guarded direct loads
#pragma unroll
            for (int c = 0; c < 4; ++c) {
                int g = base + (c << 6) + lane;
                if (g < nvec)
                    acc_vec(pred4[g], mask4[g], targ4[g], hP, hT);
            }
        }
        flush_hist(hP, hT, Plo, Phi, Tlo, Thi);   // <=16 elems per 5-bit field

        cp0 = np0; cp1 = np1; cp2 = np2; cp3 = np3;
        cm0 = nm0; cm1 = nm1; cm2 = nm2; cm3 = nm3;
        ct0 = nt0; ct1 = nt1; ct2 = nt2; ct3 = nt3;
        full = nfull;
        base = nb;
    }

    // scalar tail (n % 4)
    {
        int i = nvec * 4 + tid;
        if (i < n) {
            u64 hP = 0ull, hT = 0ull;
            acc_elem(pred[i], (unsigned)mask[i], (unsigned)targ[i], hP, hT);
            flush_hist(hP, hT, Plo, Phi, Tlo, Thi);
        }
    }

    // unpack level-2 (10-bit fields; per-thread elem count <= 1023 by grid sizing)
    unsigned vals[NCNT];
#pragma unroll
    for (int b = 0; b < 6; ++b) {
        vals[b]        = (unsigned)(Plo >> (10 * b)) & 1023u;
        vals[NBKT + b] = (unsigned)(Tlo >> (10 * b)) & 1023u;
    }
#pragma unroll
    for (int b = 6; b < NBKT; ++b) {
        vals[b]        = (unsigned)(Phi >> (10 * (b - 6))) & 1023u;
        vals[NBKT + b] = (unsigned)(Thi >> (10 * (b - 6))) & 1023u;
    }
#pragma unroll
    for (int c = 0; c < NCNT; ++c) vals[c] = wave_reduce_add(vals[c]);

    __shared__ unsigned partial[4][NCNT];
    const int wave = threadIdx.x >> 6;
    if ((threadIdx.x & 63) == 0) {
#pragma unroll
        for (int c = 0; c < NCNT; ++c) partial[wave][c] = vals[c];
    }
    __syncthreads();
    if (threadIdx.x < NCNT) {
        unsigned s = partial[0][threadIdx.x] + partial[1][threadIdx.x] +
                     partial[2][threadIdx.x] + partial[3][threadIdx.x];
        atomicAdd(&ws[threadIdx.x * WS_STRIDE], s);
    }
}

__global__ __launch_bounds__(64) void finalize_kernel(const unsigned* __restrict__ ws,
                                                      float* __restrict__ out) {
    int j = threadIdx.x;
    if (j < NTHR) {
        unsigned totM = 0u, totT = 0u, p = 0u, tp = 0u;
#pragma unroll
        for (int b = 0; b < NBKT; ++b) {
            unsigned vP = ws[b * WS_STRIDE];
            unsigned vT = ws[(NBKT + b) * WS_STRIDE];
            totM += vP; totT += vT;
            if (b > j) { p += vP; tp += vT; }
        }
        unsigned fp = p - tp;
        unsigned fn = totT - tp;
        unsigned tn = totM - p - fn;
        out[j]            = (float)tp;
        out[NTHR + j]     = (float)fp;
        out[2 * NTHR + j] = (float)tn;
        out[3 * NTHR + j] = (float)fn;
    }
}

extern "C" void kernel_launch(void* const* d_in, const int* in_sizes, int n_in,
                              void* d_out, int out_size, void* d_ws, size_t ws_size,
                              hipStream_t stream) {
    const float* pred = (const float*)d_in[0];
    const int*   mask = (const int*)d_in[1];
    const int*   targ = (const int*)d_in[2];
    unsigned*    ws   = (unsigned*)d_ws;
    float*       out  = (float*)d_out;

    const int n    = in_sizes[0];
    const int nvec = n / 4;

    zero_ws_kernel<<<1, 64, 0, stream>>>(ws);

    const int blocks = 2048;   // all resident: 8 blocks/CU at 256 thr
    count_kernel<<<blocks, 256, 0, stream>>>(
        (const float4*)pred, (const int4*)mask, (const int4*)targ,
        pred, mask, targ, ws, nvec, n);

    finalize_kernel<<<1, 64, 0, stream>>>(ws, out);
}